// Round 5
// baseline (864.558 us; speedup 1.0000x reference)
//
#include <hip/hip_runtime.h>

#define COLS 2048
#define TOPK 10

typedef float f32x4 __attribute__((ext_vector_type(4)));

// One wave (64 lanes) per row; block = 256 threads = 4 rows.
// Each block writes ONE partial; the LAST block (atomic ticket) reduces all
// partials in fixed array order (deterministic) and writes the mean.
__global__ __launch_bounds__(256, 8) void topk_mse_fused(
    const float* __restrict__ input,
    const float* __restrict__ target,
    float* __restrict__ partials,
    unsigned* __restrict__ counter,
    float* __restrict__ out,
    int nb, float inv_n)
{
    const int lane = threadIdx.x & 63;
    const int wv   = threadIdx.x >> 6;
    const int row  = (blockIdx.x << 2) + wv;

    const f32x4* rp4 = reinterpret_cast<const f32x4*>(input + (size_t)row * COLS) + lane;
    const float tgt = target[row];          // broadcast, issued early

    // ---- load 32 elements per lane, coalesced nontemporal float4 ----
    float e[32];
#pragma unroll
    for (int j = 0; j < 8; ++j) {
        f32x4 v = __builtin_nontemporal_load(rp4 + j * 64);
        e[4*j+0] = v.x; e[4*j+1] = v.y; e[4*j+2] = v.z; e[4*j+3] = v.w;
    }

    // ---- per-lane max: balanced tree (depth 5, v_max3-fusable) ----
    float m16[16];
#pragma unroll
    for (int i = 0; i < 16; ++i) m16[i] = fmaxf(e[2*i], e[2*i+1]);
#pragma unroll
    for (int i = 0; i < 8; ++i)  m16[i] = fmaxf(m16[2*i], m16[2*i+1]);
#pragma unroll
    for (int i = 0; i < 4; ++i)  m16[i] = fmaxf(m16[2*i], m16[2*i+1]);
    float m0 = fmaxf(fmaxf(m16[0], m16[1]), fmaxf(m16[2], m16[3]));

    // ---- bitonic sort of the 64 lane-maxes, ascending across lanes ----
    float s = m0;
#pragma unroll
    for (int k = 2; k <= 64; k <<= 1) {
        const bool bk = (lane & k) != 0;
#pragma unroll
        for (int j = k >> 1; j > 0; j >>= 1) {
            float p = __shfl_xor(s, j);
            const bool take_min = (((lane & j) != 0) == bk);
            s = take_min ? fminf(s, p) : fmaxf(s, p);
        }
    }
    // 10th-largest lane-max = ascending position 54; lower bound for row v10
    const float t0 = __shfl(s, 64 - TOPK);

    // ---- single rescan: wave-uniform count (SALU) + weighted sum ----
    // w(col) = 1 + 0.1*col = A(lane) + 0.1*off(slot),  A = 1 + 0.4*lane
    const float A = 1.0f + 0.4f * (float)lane;
    float s0 = 0.0f, s1 = 0.0f, s2 = 0.0f, s3 = 0.0f;
    int cnt = 0;
#pragma unroll
    for (int i = 0; i < 32; ++i) {
        const bool c = (e[i] >= t0);
        cnt += __popcll(__ballot(c));                 // wave-uniform
        const float m = c ? e[i] : 0.0f;
        const float offw = 0.1f * (float)(((i >> 2) << 8) + (i & 3));
        if ((i & 3) == 0)      { s0 = fmaf(m, A, fmaf(m, offw, s0)); }
        else if ((i & 3) == 1) { s1 = fmaf(m, A, fmaf(m, offw, s1)); }
        else if ((i & 3) == 2) { s2 = fmaf(m, A, fmaf(m, offw, s2)); }
        else                   { s3 = fmaf(m, A, fmaf(m, offw, s3)); }
    }
    float sum = (s0 + s1) + (s2 + s3);
#pragma unroll
    for (int off = 32; off >= 1; off >>= 1)
        sum += __shfl_xor(sum, off);

    // ---- drop the (cnt-10) smallest candidates; ties: remove highest col ----
    int excess = cnt - TOPK;            // >= 0 by the lane-max rank-10 bound
    unsigned removed = 0;
    while (excess > 0) {
        float lv = __builtin_inff();
        int   lc = -1;
#pragma unroll
        for (int i = 0; i < 32; ++i) {
            const int col = (lane << 2) + ((i >> 2) << 8) + (i & 3);
            const bool act = (e[i] >= t0) && !((removed >> i) & 1u);
            const bool better = act && ((e[i] < lv) || (e[i] == lv && col > lc));
            lv = better ? e[i] : lv;
            lc = better ? col  : lc;
        }
#pragma unroll
        for (int off = 32; off >= 1; off >>= 1) {
            const float pv = __shfl_xor(lv, off);
            const int   pc = __shfl_xor(lc, off);
            const bool take = (pv < lv) || (pv == lv && pc > lc);
            lv = take ? pv : lv;
            lc = take ? pc : lc;
        }
        sum -= lv * ((float)lc * 0.1f + 1.0f);      // wave-uniform
        if (((lc >> 2) & 63) == lane) {             // owner lane clears slot
            const int i = ((lc >> 8) << 2) | (lc & 3);
            removed |= (1u << i);
        }
        --excess;
    }

    // ---- block epilogue: 4 squared errors -> 1 partial ----
    __shared__ float ps[4];
    __shared__ bool is_last;
    if (lane == 0) {
        const float d = tgt - sum;
        ps[wv] = d * d;
    }
    __syncthreads();
    if (threadIdx.x == 0) {
        partials[blockIdx.x] = (ps[0] + ps[1]) + (ps[2] + ps[3]);
        __threadfence();                              // release partial
        const unsigned prev = atomicAdd(counter, 1u); // device scope
        is_last = (prev == (unsigned)(nb - 1));
    }
    __syncthreads();

    // ---- last block: reduce all partials (fixed order -> deterministic) ----
    if (is_last) {
        __threadfence();                              // acquire all partials
        const f32x4* p4 = reinterpret_cast<const f32x4*>(partials);
        const int nv = nb >> 2;
        double acc = 0.0;
        for (int i = threadIdx.x; i < nv; i += 256) {
            f32x4 v = p4[i];
            acc += (double)v.x + (double)v.y + (double)v.z + (double)v.w;
        }
#pragma unroll
        for (int off = 32; off >= 1; off >>= 1) acc += __shfl_xor(acc, off);
        __shared__ double ws[4];
        if (lane == 0) ws[wv] = acc;
        __syncthreads();
        if (threadIdx.x == 0)
            out[0] = (float)(((ws[0] + ws[1]) + (ws[2] + ws[3])) * (double)inv_n);
    }
}

extern "C" void kernel_launch(void* const* d_in, const int* in_sizes, int n_in,
                              void* d_out, int out_size, void* d_ws, size_t ws_size,
                              hipStream_t stream) {
    const float* input  = (const float*)d_in[0];
    const float* target = (const float*)d_in[1];
    float* out = (float*)d_out;

    const int rows = in_sizes[1];           // 65536
    const int nb = rows / 4;                // 16384 blocks
    const float inv_n = 1.0f / (float)rows;

    float*    partials = (float*)d_ws;                      // nb floats
    unsigned* counter  = (unsigned*)((char*)d_ws + (size_t)nb * sizeof(float));

    hipMemsetAsync(counter, 0, sizeof(unsigned), stream);   // reset ticket
    topk_mse_fused<<<nb, 256, 0, stream>>>(input, target, partials, counter,
                                           out, nb, inv_n);
}

// Round 6
// 241.621 us; speedup vs baseline: 3.5782x; 3.5782x over previous
//
#include <hip/hip_runtime.h>

#define COLS 2048
#define TOPK 10

typedef float f32x4 __attribute__((ext_vector_type(4)));

// One wave (64 lanes) per row; block = 256 threads = 4 rows.
// Each block contributes ONE pre-scaled f32 atomicAdd to out (no fences).
__global__ __launch_bounds__(256, 8) void topk_mse_kernel(
    const float* __restrict__ input,
    const float* __restrict__ target,
    float* __restrict__ out,
    float inv_n)
{
    const int lane = threadIdx.x & 63;
    const int wv   = threadIdx.x >> 6;
    const int row  = (blockIdx.x << 2) + wv;

    const f32x4* rp4 = reinterpret_cast<const f32x4*>(input + (size_t)row * COLS) + lane;
    const float tgt = target[row];          // broadcast, issued early

    // ---- load 32 elements per lane, coalesced nontemporal float4 ----
    float e[32];
#pragma unroll
    for (int j = 0; j < 8; ++j) {
        f32x4 v = __builtin_nontemporal_load(rp4 + j * 64);
        e[4*j+0] = v.x; e[4*j+1] = v.y; e[4*j+2] = v.z; e[4*j+3] = v.w;
    }

    // ---- per-lane max: balanced tree (depth 5, v_max3-fusable) ----
    float m16[16];
#pragma unroll
    for (int i = 0; i < 16; ++i) m16[i] = fmaxf(e[2*i], e[2*i+1]);
#pragma unroll
    for (int i = 0; i < 8; ++i)  m16[i] = fmaxf(m16[2*i], m16[2*i+1]);
#pragma unroll
    for (int i = 0; i < 4; ++i)  m16[i] = fmaxf(m16[2*i], m16[2*i+1]);
    float m0 = fmaxf(fmaxf(m16[0], m16[1]), fmaxf(m16[2], m16[3]));

    // ---- bitonic sort of the 64 lane-maxes, ascending across lanes ----
    float s = m0;
#pragma unroll
    for (int k = 2; k <= 64; k <<= 1) {
        const bool bk = (lane & k) != 0;
#pragma unroll
        for (int j = k >> 1; j > 0; j >>= 1) {
            float p = __shfl_xor(s, j);
            const bool take_min = (((lane & j) != 0) == bk);
            s = take_min ? fminf(s, p) : fmaxf(s, p);
        }
    }
    // 10th-largest lane-max = ascending position 54; lower bound for row v10
    const float t0 = __shfl(s, 64 - TOPK);

    // ---- single rescan: wave-uniform count + weighted sum ----
    // w(col) = 1 + 0.1*col = A(lane) + 0.1*off(slot),  A = 1 + 0.4*lane
    const float A = 1.0f + 0.4f * (float)lane;
    float s0 = 0.0f, s1 = 0.0f, s2 = 0.0f, s3 = 0.0f;
    int cnt = 0;
#pragma unroll
    for (int i = 0; i < 32; ++i) {
        const bool c = (e[i] >= t0);
        cnt += __popcll(__ballot(c));                 // wave-uniform
        const float m = c ? e[i] : 0.0f;
        const float offw = 0.1f * (float)(((i >> 2) << 8) + (i & 3));
        if ((i & 3) == 0)      { s0 = fmaf(m, A, fmaf(m, offw, s0)); }
        else if ((i & 3) == 1) { s1 = fmaf(m, A, fmaf(m, offw, s1)); }
        else if ((i & 3) == 2) { s2 = fmaf(m, A, fmaf(m, offw, s2)); }
        else                   { s3 = fmaf(m, A, fmaf(m, offw, s3)); }
    }
    float sum = (s0 + s1) + (s2 + s3);
#pragma unroll
    for (int off = 32; off >= 1; off >>= 1)
        sum += __shfl_xor(sum, off);

    // ---- drop the (cnt-10) smallest candidates; ties: remove highest col ----
    int excess = cnt - TOPK;            // >= 0 by the lane-max rank-10 bound
    unsigned removed = 0;
    while (excess > 0) {
        float lv = __builtin_inff();
        int   lc = -1;
#pragma unroll
        for (int i = 0; i < 32; ++i) {
            const int col = (lane << 2) + ((i >> 2) << 8) + (i & 3);
            const bool act = (e[i] >= t0) && !((removed >> i) & 1u);
            const bool better = act && ((e[i] < lv) || (e[i] == lv && col > lc));
            lv = better ? e[i] : lv;
            lc = better ? col  : lc;
        }
#pragma unroll
        for (int off = 32; off >= 1; off >>= 1) {
            const float pv = __shfl_xor(lv, off);
            const int   pc = __shfl_xor(lc, off);
            const bool take = (pv < lv) || (pv == lv && pc > lc);
            lv = take ? pv : lv;
            lc = take ? pc : lc;
        }
        sum -= lv * ((float)lc * 0.1f + 1.0f);      // wave-uniform
        if (((lc >> 2) & 63) == lane) {             // owner lane clears slot
            const int i = ((lc >> 8) << 2) | (lc & 3);
            removed |= (1u << i);
        }
        --excess;
    }

    // ---- block epilogue: 4 squared errors -> one atomic (no fence) ----
    __shared__ float ps[4];
    if (lane == 0) {
        const float d = tgt - sum;
        ps[wv] = d * d * inv_n;
    }
    __syncthreads();
    if (threadIdx.x == 0)
        atomicAdd(out, (ps[0] + ps[1]) + (ps[2] + ps[3]));
}

extern "C" void kernel_launch(void* const* d_in, const int* in_sizes, int n_in,
                              void* d_out, int out_size, void* d_ws, size_t ws_size,
                              hipStream_t stream) {
    const float* input  = (const float*)d_in[0];
    const float* target = (const float*)d_in[1];
    float* out = (float*)d_out;

    const int rows = in_sizes[1];           // 65536
    const int nb = rows / 4;                // 16384 blocks
    const float inv_n = 1.0f / (float)rows;

    hipMemsetAsync(out, 0, sizeof(float), stream);
    topk_mse_kernel<<<nb, 256, 0, stream>>>(input, target, out, inv_n);
}

// Round 7
// 90.732 us; speedup vs baseline: 9.5287x; 2.6630x over previous
//
#include <hip/hip_runtime.h>

#define COLS 2048
#define TOPK 10

typedef float f32x4 __attribute__((ext_vector_type(4)));

// One wave (64 lanes) per row; block = 256 threads = 4 rows.
// Each block writes ONE partial (sum of its 4 squared errors). No atomics.
// launch_bounds(256,4): 128 VGPR/lane so e[32] does NOT spill (R5 showed
// 33 MB of scratch traffic at the (256,8)/64-VGPR cap).
__global__ __launch_bounds__(256, 4) void topk_mse_main(
    const float* __restrict__ input,
    const float* __restrict__ target,
    float* __restrict__ partials)
{
    const int lane = threadIdx.x & 63;
    const int wv   = threadIdx.x >> 6;
    const int row  = (blockIdx.x << 2) + wv;

    const f32x4* rp4 = reinterpret_cast<const f32x4*>(input + (size_t)row * COLS) + lane;
    const float tgt = target[row];          // broadcast, issued early

    // ---- load 32 elements per lane, coalesced nontemporal float4 ----
    float e[32];
#pragma unroll
    for (int j = 0; j < 8; ++j) {
        f32x4 v = __builtin_nontemporal_load(rp4 + j * 64);
        e[4*j+0] = v.x; e[4*j+1] = v.y; e[4*j+2] = v.z; e[4*j+3] = v.w;
    }

    // ---- per-lane max: balanced tree (depth 5, v_max3-fusable) ----
    float m16[16];
#pragma unroll
    for (int i = 0; i < 16; ++i) m16[i] = fmaxf(e[2*i], e[2*i+1]);
#pragma unroll
    for (int i = 0; i < 8; ++i)  m16[i] = fmaxf(m16[2*i], m16[2*i+1]);
#pragma unroll
    for (int i = 0; i < 4; ++i)  m16[i] = fmaxf(m16[2*i], m16[2*i+1]);
    float m0 = fmaxf(fmaxf(m16[0], m16[1]), fmaxf(m16[2], m16[3]));

    // ---- bitonic sort of the 64 lane-maxes, ascending across lanes ----
    float s = m0;
#pragma unroll
    for (int k = 2; k <= 64; k <<= 1) {
        const bool bk = (lane & k) != 0;
#pragma unroll
        for (int j = k >> 1; j > 0; j >>= 1) {
            float p = __shfl_xor(s, j);
            const bool take_min = (((lane & j) != 0) == bk);
            s = take_min ? fminf(s, p) : fmaxf(s, p);
        }
    }
    // 10th-largest lane-max = ascending position 54; lower bound for row v10
    const float t0 = __shfl(s, 64 - TOPK);

    // ---- single rescan: wave-uniform count + weighted sum ----
    // w(col) = 1 + 0.1*col = A(lane) + 0.1*off(slot),  A = 1 + 0.4*lane
    const float A = 1.0f + 0.4f * (float)lane;
    float s0 = 0.0f, s1 = 0.0f, s2 = 0.0f, s3 = 0.0f;
    int cnt = 0;
#pragma unroll
    for (int i = 0; i < 32; ++i) {
        const bool c = (e[i] >= t0);
        cnt += __popcll(__ballot(c));                 // wave-uniform
        const float m = c ? e[i] : 0.0f;
        const float offw = 0.1f * (float)(((i >> 2) << 8) + (i & 3));
        if ((i & 3) == 0)      { s0 = fmaf(m, A, fmaf(m, offw, s0)); }
        else if ((i & 3) == 1) { s1 = fmaf(m, A, fmaf(m, offw, s1)); }
        else if ((i & 3) == 2) { s2 = fmaf(m, A, fmaf(m, offw, s2)); }
        else                   { s3 = fmaf(m, A, fmaf(m, offw, s3)); }
    }
    float sum = (s0 + s1) + (s2 + s3);
#pragma unroll
    for (int off = 32; off >= 1; off >>= 1)
        sum += __shfl_xor(sum, off);

    // ---- drop the (cnt-10) smallest candidates; ties: remove highest col ----
    int excess = cnt - TOPK;            // >= 0 by the lane-max rank-10 bound
    unsigned removed = 0;
    while (excess > 0) {
        float lv = __builtin_inff();
        int   lc = -1;
#pragma unroll
        for (int i = 0; i < 32; ++i) {
            const int col = (lane << 2) + ((i >> 2) << 8) + (i & 3);
            const bool act = (e[i] >= t0) && !((removed >> i) & 1u);
            const bool better = act && ((e[i] < lv) || (e[i] == lv && col > lc));
            lv = better ? e[i] : lv;
            lc = better ? col  : lc;
        }
#pragma unroll
        for (int off = 32; off >= 1; off >>= 1) {
            const float pv = __shfl_xor(lv, off);
            const int   pc = __shfl_xor(lc, off);
            const bool take = (pv < lv) || (pv == lv && pc > lc);
            lv = take ? pv : lv;
            lc = take ? pc : lc;
        }
        sum -= lv * ((float)lc * 0.1f + 1.0f);      // wave-uniform
        if (((lc >> 2) & 63) == lane) {             // owner lane clears slot
            const int i = ((lc >> 8) << 2) | (lc & 3);
            removed |= (1u << i);
        }
        --excess;
    }

    // ---- block epilogue: 4 squared errors -> 1 partial ----
    __shared__ float ps[4];
    if (lane == 0) {
        const float d = tgt - sum;
        ps[wv] = d * d;
    }
    __syncthreads();
    if (threadIdx.x == 0)
        partials[blockIdx.x] = (ps[0] + ps[1]) + (ps[2] + ps[3]);
}

// Final reduction: 1 block, 256 threads, float4 loads, f64 accumulate.
__global__ __launch_bounds__(256) void topk_mse_reduce(
    const float* __restrict__ partials,
    float* __restrict__ out,
    int nb, float inv_n)
{
    const f32x4* p4 = reinterpret_cast<const f32x4*>(partials);
    const int nv = nb >> 2;                 // float4 count
    double s = 0.0;
    for (int i = threadIdx.x; i < nv; i += 256) {
        f32x4 v = p4[i];
        s += (double)v.x + (double)v.y + (double)v.z + (double)v.w;
    }
#pragma unroll
    for (int off = 32; off >= 1; off >>= 1) s += __shfl_xor(s, off);
    __shared__ double ws[4];
    const int wv = threadIdx.x >> 6;
    if ((threadIdx.x & 63) == 0) ws[wv] = s;
    __syncthreads();
    if (threadIdx.x == 0)
        out[0] = (float)(((ws[0] + ws[1]) + (ws[2] + ws[3])) * (double)inv_n);
}

extern "C" void kernel_launch(void* const* d_in, const int* in_sizes, int n_in,
                              void* d_out, int out_size, void* d_ws, size_t ws_size,
                              hipStream_t stream) {
    const float* input  = (const float*)d_in[0];
    const float* target = (const float*)d_in[1];
    float* out = (float*)d_out;
    float* partials = (float*)d_ws;         // nb * 4 bytes, well under ws_size

    const int rows = in_sizes[1];           // 65536
    const int nb = rows / 4;                // 16384 blocks
    const float inv_n = 1.0f / (float)rows;

    topk_mse_main<<<nb, 256, 0, stream>>>(input, target, partials);
    topk_mse_reduce<<<1, 256, 0, stream>>>(partials, out, nb, inv_n);
}